// Round 4
// baseline (836.111 us; speedup 1.0000x reference)
//
#include <hip/hip_runtime.h>

#define NT 8
#define ND 16
#define NH 16
#define NW 16
#define NC 32
#define NB 65536

typedef __attribute__((ext_vector_type(8))) _Float16 half8;
typedef __attribute__((ext_vector_type(4))) _Float16 half4;

// Span-based per-dim setup: control-point span b..b+3 (always in-bounds) and
// 4 weights aligned to the span, with linear-extrapolation padding folded in
// and zero-padding at the edges. Equivalent to padded-grid reference.
template <int N>
__device__ __forceinline__ void dim_setup_span(float u, int& b, float w[4]) {
    float s = u * (float)(N - 1);
    float fi = floorf(s);
    fi = fminf(fmaxf(fi, 0.0f), (float)(N - 2));
    float t = s - fi;
    int i = (int)fi;
    float t2 = t * t, t3 = t2 * t;
    const float c6 = 1.0f / 6.0f;
    float w0 = (1.0f - 3.0f * t + 3.0f * t2 - t3) * c6;
    float w1 = (4.0f - 6.0f * t2 + 3.0f * t3) * c6;
    float w2 = (1.0f + 3.0f * t + 3.0f * t2 - 3.0f * t3) * c6;
    float w3 = t3 * c6;
    if (i == 0) {
        // phantom point -1 = 2*g0 - g1 folded onto points 0,1,2; span 0..3
        b = 0;
        w[0] = w1 + 2.0f * w0; w[1] = w2 - w0; w[2] = w3; w[3] = 0.0f;
    } else if (i == N - 2) {
        // phantom point N = 2*g[N-1] - g[N-2] folded onto N-3..N-1; span N-4..N-1
        b = N - 4;
        w[0] = 0.0f; w[1] = w0; w[2] = w1 - w3; w[3] = w2 + 2.0f * w3;
    } else {
        b = i - 1;
        w[0] = w0; w[1] = w1; w[2] = w2; w[3] = w3;
    }
}

// f32 grid (4 MiB) -> fp16 grid (2 MiB) in workspace, RNE.
__global__ __launch_bounds__(256) void convert_fp16_kernel(
    const float4* __restrict__ g, half4* __restrict__ hg) {
    int i = blockIdx.x * blockDim.x + threadIdx.x;
    float4 v = g[i];
    half4 h;
    h[0] = (_Float16)v.x;
    h[1] = (_Float16)v.y;
    h[2] = (_Float16)v.z;
    h[3] = (_Float16)v.w;
    hg[i] = h;
}

// 8 lanes per query. The 4 w-span points are CONTIGUOUS in memory
// (4 pts x 32ch x 2B = 256B). Lane s loads 16B at span+16*s (w-point s>>2,
// channels 8*(s&3)..+8) and 16B at span+128+16*s (w-point 2+(s>>2), same
// channels): 2 loads per lane per (t,d,h) -> 128 gather loads/lane total.
__global__ __launch_bounds__(256, 4) void spline4d_fp16_kernel(
    const float* __restrict__ u, const half8* __restrict__ grid,
    float4* __restrict__ out) {
    int tid = blockIdx.x * blockDim.x + threadIdx.x;
    int q = tid >> 3;
    int s = tid & 7;

    float4 uu = reinterpret_cast<const float4*>(u)[q];

    int bt, bd, bh, bw;
    float wtv[4], wdv[4], whv[4], wwv[4];
    dim_setup_span<NT>(uu.x, bt, wtv);
    dim_setup_span<ND>(uu.y, bd, wdv);
    dim_setup_span<NH>(uu.z, bh, whv);
    dim_setup_span<NW>(uu.w, bw, wwv);

    bool hi = (s >= 4);
    float wA = hi ? wwv[1] : wwv[0];   // weight of w-point (s>>2)
    float wB = hi ? wwv[3] : wwv[2];   // weight of w-point 2+(s>>2)

    // fold lane's w-weights into the h weights
    float whA[4], whB[4];
#pragma unroll
    for (int k = 0; k < 4; ++k) {
        whA[k] = whv[k] * wA;
        whB[k] = whv[k] * wB;
    }

    // half8 index of lane's first load for the span at (bt,bd,bh,bw):
    // point index P = ((t*16+d)*16+h)*16+w ; half8 idx = P*4 + s
    int base = ((((bt * ND + bd) * NH + bh) * NW + bw) << 2) + s;

    float acc[8];
#pragma unroll
    for (int c = 0; c < 8; ++c) acc[c] = 0.0f;

#pragma unroll
    for (int i = 0; i < 4; ++i) {
#pragma unroll
        for (int j = 0; j < 4; ++j) {
            float wtd = wtv[i] * wdv[j];
#pragma unroll
            for (int k = 0; k < 4; ++k) {
                int a = base + i * (4 * ND * NH * NW) + j * (4 * NH * NW) + k * (4 * NW);
                half8 A = grid[a];
                half8 B = grid[a + 8];
                float uw = wtd * whA[k];
                float vw = wtd * whB[k];
                acc[0] = fmaf((float)A[0], uw, acc[0]);
                acc[1] = fmaf((float)A[1], uw, acc[1]);
                acc[2] = fmaf((float)A[2], uw, acc[2]);
                acc[3] = fmaf((float)A[3], uw, acc[3]);
                acc[4] = fmaf((float)A[4], uw, acc[4]);
                acc[5] = fmaf((float)A[5], uw, acc[5]);
                acc[6] = fmaf((float)A[6], uw, acc[6]);
                acc[7] = fmaf((float)A[7], uw, acc[7]);
                acc[0] = fmaf((float)B[0], vw, acc[0]);
                acc[1] = fmaf((float)B[1], vw, acc[1]);
                acc[2] = fmaf((float)B[2], vw, acc[2]);
                acc[3] = fmaf((float)B[3], vw, acc[3]);
                acc[4] = fmaf((float)B[4], vw, acc[4]);
                acc[5] = fmaf((float)B[5], vw, acc[5]);
                acc[6] = fmaf((float)B[6], vw, acc[6]);
                acc[7] = fmaf((float)B[7], vw, acc[7]);
            }
        }
    }

    // lanes s and s^4 hold the same channels (different w-points): reduce.
#pragma unroll
    for (int c = 0; c < 8; ++c) acc[c] += __shfl_xor(acc[c], 4);

    // lanes 0..3 hold channels 8s..8s+8 -> two float4 stores each
    if (!hi) {
        out[q * 8 + s * 2] = make_float4(acc[0], acc[1], acc[2], acc[3]);
        out[q * 8 + s * 2 + 1] = make_float4(acc[4], acc[5], acc[6], acc[7]);
    }
}

// Fallback (workspace too small): f32 gather kernel (round-1 version).
#define SW 8
#define SH (NW * SW)
#define SD (NH * SH)
#define ST (ND * SD)

template <int N, int STRIDE>
__device__ __forceinline__ void dim_setup(float u, int idx[4], float w[4]) {
    float s = u * (float)(N - 1);
    float fi = floorf(s);
    fi = fminf(fmaxf(fi, 0.0f), (float)(N - 2));
    float t = s - fi;
    int i = (int)fi;
    float t2 = t * t, t3 = t2 * t;
    const float c6 = 1.0f / 6.0f;
    float w0 = (1.0f - 3.0f * t + 3.0f * t2 - t3) * c6;
    float w1 = (4.0f - 6.0f * t2 + 3.0f * t3) * c6;
    float w2 = (1.0f + 3.0f * t + 3.0f * t2 - 3.0f * t3) * c6;
    float w3 = t3 * c6;
    int i0, i1, i2, i3;
    float v0, v1, v2, v3;
    if (i == 0) {
        i0 = 0; i1 = 1; i2 = 2; i3 = 2;
        v0 = w1 + 2.0f * w0; v1 = w2 - w0; v2 = w3; v3 = 0.0f;
    } else if (i == N - 2) {
        i0 = N - 3; i1 = N - 2; i2 = N - 1; i3 = N - 1;
        v0 = w0; v1 = w1 - w3; v2 = w2 + 2.0f * w3; v3 = 0.0f;
    } else {
        i0 = i - 1; i1 = i; i2 = i + 1; i3 = i + 2;
        v0 = w0; v1 = w1; v2 = w2; v3 = w3;
    }
    idx[0] = i0 * STRIDE; idx[1] = i1 * STRIDE;
    idx[2] = i2 * STRIDE; idx[3] = i3 * STRIDE;
    w[0] = v0; w[1] = v1; w[2] = v2; w[3] = v3;
}

__global__ __launch_bounds__(256, 4) void spline4d_f32_kernel(
    const float* __restrict__ u, const float4* __restrict__ grid,
    float4* __restrict__ out) {
    int tid = blockIdx.x * blockDim.x + threadIdx.x;
    int q = tid >> 3;
    int s = tid & 7;

    float4 uu = reinterpret_cast<const float4*>(u)[q];

    int it[4], id[4], ih[4], iw[4];
    float wt[4], wd[4], wh[4], ww[4];
    dim_setup<NT, ST>(uu.x, it, wt);
    dim_setup<ND, SD>(uu.y, id, wd);
    dim_setup<NH, SH>(uu.z, ih, wh);
    dim_setup<NW, SW>(uu.w, iw, ww);

    float4 acc = make_float4(0.0f, 0.0f, 0.0f, 0.0f);

#pragma unroll
    for (int i = 0; i < 4; ++i) {
        int offt = it[i];
        float wti = wt[i];
#pragma unroll
        for (int j = 0; j < 4; ++j) {
            int offtd = offt + id[j];
            float wij = wti * wd[j];
#pragma unroll
            for (int k = 0; k < 4; ++k) {
                int offtdh = offtd + ih[k] + s;
                float wijk = wij * wh[k];
#pragma unroll
                for (int l = 0; l < 4; ++l) {
                    float4 p = grid[offtdh + iw[l]];
                    float wgt = wijk * ww[l];
                    acc.x = fmaf(wgt, p.x, acc.x);
                    acc.y = fmaf(wgt, p.y, acc.y);
                    acc.z = fmaf(wgt, p.z, acc.z);
                    acc.w = fmaf(wgt, p.w, acc.w);
                }
            }
        }
    }

    out[q * 8 + s] = acc;
}

extern "C" void kernel_launch(void* const* d_in, const int* in_sizes, int n_in,
                              void* d_out, int out_size, void* d_ws, size_t ws_size,
                              hipStream_t stream) {
    const float* u = (const float*)d_in[0];
    const float* grid_f32 = (const float*)d_in[1];
    float4* out = (float4*)d_out;

    const size_t n_grid_floats = (size_t)NT * ND * NH * NW * NC;  // 1,048,576
    const size_t hg_bytes = n_grid_floats * 2;                    // 2 MiB

    int total_threads = NB * 8;
    int block = 256;
    int nblocks = total_threads / block;  // 2048

    if (ws_size >= hg_bytes) {
        half8* hgrid = (half8*)d_ws;
        int cvt_blocks = (int)(n_grid_floats / 4 / 256);  // 1024
        convert_fp16_kernel<<<cvt_blocks, 256, 0, stream>>>(
            (const float4*)grid_f32, (half4*)d_ws);
        spline4d_fp16_kernel<<<nblocks, block, 0, stream>>>(u, hgrid, out);
    } else {
        spline4d_f32_kernel<<<nblocks, block, 0, stream>>>(
            u, (const float4*)grid_f32, out);
    }
}

// Round 5
// 56.089 us; speedup vs baseline: 14.9070x; 14.9070x over previous
//
#include <hip/hip_runtime.h>

#define NT 8
#define ND 16
#define NH 16
#define NW 16
#define NC 32
#define NB 65536

typedef __attribute__((ext_vector_type(8))) _Float16 half8;
typedef __attribute__((ext_vector_type(4))) _Float16 half4;

// Span-based per-dim setup: control-point span b..b+3 (always in-bounds) and
// 4 weights aligned to the span, with linear-extrapolation padding folded in
// and zero-padding at the edges. Validated (absmax 7.8e-3) in rounds 3/4.
template <int N>
__device__ __forceinline__ void dim_setup_span(float u, int& b, float w[4]) {
    float s = u * (float)(N - 1);
    float fi = floorf(s);
    fi = fminf(fmaxf(fi, 0.0f), (float)(N - 2));
    float t = s - fi;
    int i = (int)fi;
    float t2 = t * t, t3 = t2 * t;
    const float c6 = 1.0f / 6.0f;
    float w0 = (1.0f - 3.0f * t + 3.0f * t2 - t3) * c6;
    float w1 = (4.0f - 6.0f * t2 + 3.0f * t3) * c6;
    float w2 = (1.0f + 3.0f * t + 3.0f * t2 - 3.0f * t3) * c6;
    float w3 = t3 * c6;
    if (i == 0) {
        b = 0;
        w[0] = w1 + 2.0f * w0; w[1] = w2 - w0; w[2] = w3; w[3] = 0.0f;
    } else if (i == N - 2) {
        b = N - 4;
        w[0] = 0.0f; w[1] = w0; w[2] = w1 - w3; w[3] = w2 + 2.0f * w3;
    } else {
        b = i - 1;
        w[0] = w0; w[1] = w1; w[2] = w2; w[3] = w3;
    }
}

// f32 grid (4 MiB) -> fp16 grid (2 MiB) in workspace, RNE.
__global__ __launch_bounds__(256) void convert_fp16_kernel(
    const float4* __restrict__ g, half4* __restrict__ hg) {
    int i = blockIdx.x * blockDim.x + threadIdx.x;
    float4 v = g[i];
    half4 h;
    h[0] = (_Float16)v.x;
    h[1] = (_Float16)v.y;
    h[2] = (_Float16)v.z;
    h[3] = (_Float16)v.w;
    hg[i] = h;
}

// 16 lanes per query. The 4-point w-span is 256B contiguous (4 x 32ch x 2B);
// lane s takes 16B at byte offset 16*s: w-point (s>>2), channels 8*(s&3)..+8.
// One half8 load per lane per (t,d,h) -> 64 gather instrs/lane (vs 256 in r3).
// Cross-lane reduce over w-points via shfl_xor(4) and shfl_xor(8).
__global__ __launch_bounds__(256) void spline4d_fp16_kernel(
    const float* __restrict__ u, const half8* __restrict__ grid,
    float4* __restrict__ out) {
    int tid = blockIdx.x * blockDim.x + threadIdx.x;
    int q = tid >> 4;   // query index
    int s = tid & 15;   // lane-within-query

    float4 uu = reinterpret_cast<const float4*>(u)[q];

    int bt, bd, bh, bw;
    float wtv[4], wdv[4], whv[4], wwv[4];
    dim_setup_span<NT>(uu.x, bt, wtv);
    dim_setup_span<ND>(uu.y, bd, wdv);
    dim_setup_span<NH>(uu.z, bh, whv);
    dim_setup_span<NW>(uu.w, bw, wwv);

    // this lane's w-point weight (static-index select, avoids scratch)
    int wp = s >> 2;
    float wlane = (wp & 2) ? ((wp & 1) ? wwv[3] : wwv[2])
                           : ((wp & 1) ? wwv[1] : wwv[0]);

    // fold lane's w-weight into the h weights
    float whW[4];
#pragma unroll
    for (int k = 0; k < 4; ++k) whW[k] = whv[k] * wlane;

    // half8 index: point P = ((t*ND+d)*NH+h)*NW+w occupies half8 [4P, 4P+4);
    // lane covers span byte offset 16*s -> half8 index 4*P_base + s.
    int base = ((((bt * ND + bd) * NH + bh) * NW + bw) << 2) + s;

    float acc[8];
#pragma unroll
    for (int c = 0; c < 8; ++c) acc[c] = 0.0f;

#pragma unroll
    for (int i = 0; i < 4; ++i) {
#pragma unroll
        for (int j = 0; j < 4; ++j) {
            float wtd = wtv[i] * wdv[j];
#pragma unroll
            for (int k = 0; k < 4; ++k) {
                // point strides: t = ND*NH*NW = 4096 pts, d = 256, h = 16
                int a = base + i * (4 * ND * NH * NW) + j * (4 * NH * NW) + k * (4 * NW);
                half8 A = grid[a];
                float uw = wtd * whW[k];
                acc[0] = fmaf((float)A[0], uw, acc[0]);
                acc[1] = fmaf((float)A[1], uw, acc[1]);
                acc[2] = fmaf((float)A[2], uw, acc[2]);
                acc[3] = fmaf((float)A[3], uw, acc[3]);
                acc[4] = fmaf((float)A[4], uw, acc[4]);
                acc[5] = fmaf((float)A[5], uw, acc[5]);
                acc[6] = fmaf((float)A[6], uw, acc[6]);
                acc[7] = fmaf((float)A[7], uw, acc[7]);
            }
        }
    }

    // combine the 4 w-points: lanes s, s^4, s^8, s^12 share channels 8*(s&3)
#pragma unroll
    for (int c = 0; c < 8; ++c) {
        acc[c] += __shfl_xor(acc[c], 4);
        acc[c] += __shfl_xor(acc[c], 8);
    }

    // lanes 0..3 hold channels 8s..8s+7 -> two float4 stores each
    if (s < 4) {
        out[q * 8 + s * 2] = make_float4(acc[0], acc[1], acc[2], acc[3]);
        out[q * 8 + s * 2 + 1] = make_float4(acc[4], acc[5], acc[6], acc[7]);
    }
}

// Fallback (workspace too small): f32 gather kernel (round-1 version, passed).
#define SW 8
#define SH (NW * SW)
#define SD (NH * SH)
#define ST (ND * SD)

template <int N, int STRIDE>
__device__ __forceinline__ void dim_setup(float u, int idx[4], float w[4]) {
    float s = u * (float)(N - 1);
    float fi = floorf(s);
    fi = fminf(fmaxf(fi, 0.0f), (float)(N - 2));
    float t = s - fi;
    int i = (int)fi;
    float t2 = t * t, t3 = t2 * t;
    const float c6 = 1.0f / 6.0f;
    float w0 = (1.0f - 3.0f * t + 3.0f * t2 - t3) * c6;
    float w1 = (4.0f - 6.0f * t2 + 3.0f * t3) * c6;
    float w2 = (1.0f + 3.0f * t + 3.0f * t2 - 3.0f * t3) * c6;
    float w3 = t3 * c6;
    int i0, i1, i2, i3;
    float v0, v1, v2, v3;
    if (i == 0) {
        i0 = 0; i1 = 1; i2 = 2; i3 = 2;
        v0 = w1 + 2.0f * w0; v1 = w2 - w0; v2 = w3; v3 = 0.0f;
    } else if (i == N - 2) {
        i0 = N - 3; i1 = N - 2; i2 = N - 1; i3 = N - 1;
        v0 = w0; v1 = w1 - w3; v2 = w2 + 2.0f * w3; v3 = 0.0f;
    } else {
        i0 = i - 1; i1 = i; i2 = i + 1; i3 = i + 2;
        v0 = w0; v1 = w1; v2 = w2; v3 = w3;
    }
    idx[0] = i0 * STRIDE; idx[1] = i1 * STRIDE;
    idx[2] = i2 * STRIDE; idx[3] = i3 * STRIDE;
    w[0] = v0; w[1] = v1; w[2] = v2; w[3] = v3;
}

__global__ __launch_bounds__(256, 4) void spline4d_f32_kernel(
    const float* __restrict__ u, const float4* __restrict__ grid,
    float4* __restrict__ out) {
    int tid = blockIdx.x * blockDim.x + threadIdx.x;
    int q = tid >> 3;
    int s = tid & 7;

    float4 uu = reinterpret_cast<const float4*>(u)[q];

    int it[4], id[4], ih[4], iw[4];
    float wt[4], wd[4], wh[4], ww[4];
    dim_setup<NT, ST>(uu.x, it, wt);
    dim_setup<ND, SD>(uu.y, id, wd);
    dim_setup<NH, SH>(uu.z, ih, wh);
    dim_setup<NW, SW>(uu.w, iw, ww);

    float4 acc = make_float4(0.0f, 0.0f, 0.0f, 0.0f);

#pragma unroll
    for (int i = 0; i < 4; ++i) {
        int offt = it[i];
        float wti = wt[i];
#pragma unroll
        for (int j = 0; j < 4; ++j) {
            int offtd = offt + id[j];
            float wij = wti * wd[j];
#pragma unroll
            for (int k = 0; k < 4; ++k) {
                int offtdh = offtd + ih[k] + s;
                float wijk = wij * wh[k];
#pragma unroll
                for (int l = 0; l < 4; ++l) {
                    float4 p = grid[offtdh + iw[l]];
                    float wgt = wijk * ww[l];
                    acc.x = fmaf(wgt, p.x, acc.x);
                    acc.y = fmaf(wgt, p.y, acc.y);
                    acc.z = fmaf(wgt, p.z, acc.z);
                    acc.w = fmaf(wgt, p.w, acc.w);
                }
            }
        }
    }

    out[q * 8 + s] = acc;
}

extern "C" void kernel_launch(void* const* d_in, const int* in_sizes, int n_in,
                              void* d_out, int out_size, void* d_ws, size_t ws_size,
                              hipStream_t stream) {
    const float* u = (const float*)d_in[0];
    const float* grid_f32 = (const float*)d_in[1];
    float4* out = (float4*)d_out;

    const size_t n_grid_floats = (size_t)NT * ND * NH * NW * NC;  // 1,048,576
    const size_t hg_bytes = n_grid_floats * 2;                    // 2 MiB

    if (ws_size >= hg_bytes) {
        int cvt_blocks = (int)(n_grid_floats / 4 / 256);  // 1024
        convert_fp16_kernel<<<cvt_blocks, 256, 0, stream>>>(
            (const float4*)grid_f32, (half4*)d_ws);
        // 16 threads per query, 256/block -> 16 queries/block, 4096 blocks
        int nblocks = NB * 16 / 256;
        spline4d_fp16_kernel<<<nblocks, 256, 0, stream>>>(
            u, (const half8*)d_ws, out);
    } else {
        int nblocks = NB * 8 / 256;
        spline4d_f32_kernel<<<nblocks, 256, 0, stream>>>(
            u, (const float4*)grid_f32, out);
    }
}

// Round 6
// 52.671 us; speedup vs baseline: 15.8742x; 1.0649x over previous
//
#include <hip/hip_runtime.h>

#define NT 8
#define ND 16
#define NH 16
#define NW 16
#define NC 32
#define NB 65536

typedef __attribute__((ext_vector_type(8))) _Float16 half8;
typedef __attribute__((ext_vector_type(4))) _Float16 half4;
typedef __attribute__((ext_vector_type(2))) _Float16 half2v;

union H8 {
    half8 v;
    half2v h2[4];
};

// Span-based per-dim setup: control-point span b..b+3 (always in-bounds) and
// 4 weights aligned to the span, with linear-extrapolation padding folded in
// and zero-padding at the edges. Validated (absmax 7.8e-3) in rounds 3-5.
template <int N>
__device__ __forceinline__ void dim_setup_span(float u, int& b, float w[4]) {
    float s = u * (float)(N - 1);
    float fi = floorf(s);
    fi = fminf(fmaxf(fi, 0.0f), (float)(N - 2));
    float t = s - fi;
    int i = (int)fi;
    float t2 = t * t, t3 = t2 * t;
    const float c6 = 1.0f / 6.0f;
    float w0 = (1.0f - 3.0f * t + 3.0f * t2 - t3) * c6;
    float w1 = (4.0f - 6.0f * t2 + 3.0f * t3) * c6;
    float w2 = (1.0f + 3.0f * t + 3.0f * t2 - 3.0f * t3) * c6;
    float w3 = t3 * c6;
    if (i == 0) {
        b = 0;
        w[0] = w1 + 2.0f * w0; w[1] = w2 - w0; w[2] = w3; w[3] = 0.0f;
    } else if (i == N - 2) {
        b = N - 4;
        w[0] = 0.0f; w[1] = w0; w[2] = w1 - w3; w[3] = w2 + 2.0f * w3;
    } else {
        b = i - 1;
        w[0] = w0; w[1] = w1; w[2] = w2; w[3] = w3;
    }
}

// f32 grid (4 MiB) -> fp16 grid (2 MiB) in workspace, RNE.
__global__ __launch_bounds__(256) void convert_fp16_kernel(
    const float4* __restrict__ g, half4* __restrict__ hg) {
    int i = blockIdx.x * blockDim.x + threadIdx.x;
    float4 v = g[i];
    half4 h;
    h[0] = (_Float16)v.x;
    h[1] = (_Float16)v.y;
    h[2] = (_Float16)v.z;
    h[3] = (_Float16)v.w;
    hg[i] = h;
}

// 16 lanes per query; lane s takes 16B of the contiguous 256B w-span
// (w-point s>>2, channels 8*(s&3)..+8); one half8 load per (t,d,h).
// Accumulation in packed f16 (v_pk_fma_f16), flushed to f32 every 2 t-steps
// (max 128 f16-accumulated terms) to bound rounding.
__global__ __launch_bounds__(256) void spline4d_fp16_kernel(
    const float* __restrict__ u, const half8* __restrict__ grid,
    float4* __restrict__ out) {
    int tid = blockIdx.x * blockDim.x + threadIdx.x;
    int q = tid >> 4;   // query index
    int s = tid & 15;   // lane-within-query

    float4 uu = reinterpret_cast<const float4*>(u)[q];

    int bt, bd, bh, bw;
    float wtv[4], wdv[4], whv[4], wwv[4];
    dim_setup_span<NT>(uu.x, bt, wtv);
    dim_setup_span<ND>(uu.y, bd, wdv);
    dim_setup_span<NH>(uu.z, bh, whv);
    dim_setup_span<NW>(uu.w, bw, wwv);

    // this lane's w-point weight (static-index select chain, avoids scratch)
    int wp = s >> 2;
    float wlane = (wp & 2) ? ((wp & 1) ? wwv[3] : wwv[2])
                           : ((wp & 1) ? wwv[1] : wwv[0]);

    // pre-packed half2 broadcast of (h-weight x lane w-weight)
    half2v whW2[4];
#pragma unroll
    for (int k = 0; k < 4; ++k) {
        _Float16 h = (_Float16)(whv[k] * wlane);
        whW2[k][0] = h;
        whW2[k][1] = h;
    }

    // half8 index: point P = ((t*ND+d)*NH+h)*NW+w occupies half8 [4P, 4P+4);
    // lane covers span byte offset 16*s -> half8 index 4*P_base + s.
    int base = ((((bt * ND + bd) * NH + bh) * NW + bw) << 2) + s;

    float facc[8];
#pragma unroll
    for (int c = 0; c < 8; ++c) facc[c] = 0.0f;

    half2v a01 = {0, 0}, a23 = {0, 0}, a45 = {0, 0}, a67 = {0, 0};

#pragma unroll
    for (int i = 0; i < 4; ++i) {
#pragma unroll
        for (int j = 0; j < 4; ++j) {
            _Float16 wtdh = (_Float16)(wtv[i] * wdv[j]);
            half2v wtd2 = {wtdh, wtdh};
#pragma unroll
            for (int k = 0; k < 4; ++k) {
                int a = base + i * (4 * ND * NH * NW) + j * (4 * NH * NW) + k * (4 * NW);
                H8 P;
                P.v = grid[a];
                half2v uw2 = wtd2 * whW2[k];   // v_pk_mul_f16
                a01 += P.h2[0] * uw2;          // v_pk_fma_f16
                a23 += P.h2[1] * uw2;
                a45 += P.h2[2] * uw2;
                a67 += P.h2[3] * uw2;
            }
        }
        if (i == 1 || i == 3) {
            // flush f16 partials (max 128 terms) into f32
            facc[0] += (float)a01[0]; facc[1] += (float)a01[1];
            facc[2] += (float)a23[0]; facc[3] += (float)a23[1];
            facc[4] += (float)a45[0]; facc[5] += (float)a45[1];
            facc[6] += (float)a67[0]; facc[7] += (float)a67[1];
            a01 = (half2v){0, 0}; a23 = (half2v){0, 0};
            a45 = (half2v){0, 0}; a67 = (half2v){0, 0};
        }
    }

    // combine the 4 w-points: lanes s, s^4, s^8, s^12 share channels 8*(s&3)
#pragma unroll
    for (int c = 0; c < 8; ++c) {
        facc[c] += __shfl_xor(facc[c], 4);
        facc[c] += __shfl_xor(facc[c], 8);
    }

    // lanes 0..3 hold channels 8s..8s+7 -> two float4 stores each
    if (s < 4) {
        out[q * 8 + s * 2] = make_float4(facc[0], facc[1], facc[2], facc[3]);
        out[q * 8 + s * 2 + 1] = make_float4(facc[4], facc[5], facc[6], facc[7]);
    }
}

// Fallback (workspace too small): f32 gather kernel (round-1 version, passed).
#define SW 8
#define SH (NW * SW)
#define SD (NH * SH)
#define ST (ND * SD)

template <int N, int STRIDE>
__device__ __forceinline__ void dim_setup(float u, int idx[4], float w[4]) {
    float s = u * (float)(N - 1);
    float fi = floorf(s);
    fi = fminf(fmaxf(fi, 0.0f), (float)(N - 2));
    float t = s - fi;
    int i = (int)fi;
    float t2 = t * t, t3 = t2 * t;
    const float c6 = 1.0f / 6.0f;
    float w0 = (1.0f - 3.0f * t + 3.0f * t2 - t3) * c6;
    float w1 = (4.0f - 6.0f * t2 + 3.0f * t3) * c6;
    float w2 = (1.0f + 3.0f * t + 3.0f * t2 - 3.0f * t3) * c6;
    float w3 = t3 * c6;
    int i0, i1, i2, i3;
    float v0, v1, v2, v3;
    if (i == 0) {
        i0 = 0; i1 = 1; i2 = 2; i3 = 2;
        v0 = w1 + 2.0f * w0; v1 = w2 - w0; v2 = w3; v3 = 0.0f;
    } else if (i == N - 2) {
        i0 = N - 3; i1 = N - 2; i2 = N - 1; i3 = N - 1;
        v0 = w0; v1 = w1 - w3; v2 = w2 + 2.0f * w3; v3 = 0.0f;
    } else {
        i0 = i - 1; i1 = i; i2 = i + 1; i3 = i + 2;
        v0 = w0; v1 = w1; v2 = w2; v3 = w3;
    }
    idx[0] = i0 * STRIDE; idx[1] = i1 * STRIDE;
    idx[2] = i2 * STRIDE; idx[3] = i3 * STRIDE;
    w[0] = v0; w[1] = v1; w[2] = v2; w[3] = v3;
}

__global__ __launch_bounds__(256, 4) void spline4d_f32_kernel(
    const float* __restrict__ u, const float4* __restrict__ grid,
    float4* __restrict__ out) {
    int tid = blockIdx.x * blockDim.x + threadIdx.x;
    int q = tid >> 3;
    int s = tid & 7;

    float4 uu = reinterpret_cast<const float4*>(u)[q];

    int it[4], id[4], ih[4], iw[4];
    float wt[4], wd[4], wh[4], ww[4];
    dim_setup<NT, ST>(uu.x, it, wt);
    dim_setup<ND, SD>(uu.y, id, wd);
    dim_setup<NH, SH>(uu.z, ih, wh);
    dim_setup<NW, SW>(uu.w, iw, ww);

    float4 acc = make_float4(0.0f, 0.0f, 0.0f, 0.0f);

#pragma unroll
    for (int i = 0; i < 4; ++i) {
        int offt = it[i];
        float wti = wt[i];
#pragma unroll
        for (int j = 0; j < 4; ++j) {
            int offtd = offt + id[j];
            float wij = wti * wd[j];
#pragma unroll
            for (int k = 0; k < 4; ++k) {
                int offtdh = offtd + ih[k] + s;
                float wijk = wij * wh[k];
#pragma unroll
                for (int l = 0; l < 4; ++l) {
                    float4 p = grid[offtdh + iw[l]];
                    float wgt = wijk * ww[l];
                    acc.x = fmaf(wgt, p.x, acc.x);
                    acc.y = fmaf(wgt, p.y, acc.y);
                    acc.z = fmaf(wgt, p.z, acc.z);
                    acc.w = fmaf(wgt, p.w, acc.w);
                }
            }
        }
    }

    out[q * 8 + s] = acc;
}

extern "C" void kernel_launch(void* const* d_in, const int* in_sizes, int n_in,
                              void* d_out, int out_size, void* d_ws, size_t ws_size,
                              hipStream_t stream) {
    const float* u = (const float*)d_in[0];
    const float* grid_f32 = (const float*)d_in[1];
    float4* out = (float4*)d_out;

    const size_t n_grid_floats = (size_t)NT * ND * NH * NW * NC;  // 1,048,576
    const size_t hg_bytes = n_grid_floats * 2;                    // 2 MiB

    if (ws_size >= hg_bytes) {
        int cvt_blocks = (int)(n_grid_floats / 4 / 256);  // 1024
        convert_fp16_kernel<<<cvt_blocks, 256, 0, stream>>>(
            (const float4*)grid_f32, (half4*)d_ws);
        // 16 threads per query, 256/block -> 16 queries/block, 4096 blocks
        int nblocks = NB * 16 / 256;
        spline4d_fp16_kernel<<<nblocks, 256, 0, stream>>>(
            u, (const half8*)d_ws, out);
    } else {
        int nblocks = NB * 8 / 256;
        spline4d_f32_kernel<<<nblocks, 256, 0, stream>>>(
            u, (const float4*)grid_f32, out);
    }
}